// Round 4
// baseline (5391.573 us; speedup 1.0000x reference)
//
#include <hip/hip_runtime.h>

#define TLEN 2048
#define BATCH 32
#define DIN 64
#define HID 128

typedef _Float16 h2 __attribute__((ext_vector_type(2)));
typedef float f4 __attribute__((ext_vector_type(4)));
typedef unsigned int u32;

#if defined(__has_builtin)
#if __has_builtin(__builtin_amdgcn_fdot2)
#define FDOT2(a, b, c) __builtin_amdgcn_fdot2((a), (b), (c), false)
#endif
#endif
#ifndef FDOT2
#define FDOT2(a, b, c) ((c) + (float)(a).x * (float)(b).x + (float)(a).y * (float)(b).y)
#endif

__device__ __forceinline__ float sigm(float x) { return 1.0f / (1.0f + __expf(-x)); }
__device__ __forceinline__ float tanh_c(float x) {
    x = fminf(fmaxf(x, -15.0f), 15.0f);
    float e = __expf(2.0f * x);
    return (e - 1.0f) / (e + 1.0f);
}

// 3-stage butterfly over 8-lane groups (R1-proven __shfl_xor idiom, width 8)
__device__ __forceinline__ void qreduce8(float (&v)[4]) {
    #pragma unroll
    for (int m = 0; m < 4; ++m) {
        v[m] += __shfl_xor(v[m], 1, 8);
        v[m] += __shfl_xor(v[m], 2, 8);
        v[m] += __shfl_xor(v[m], 4, 8);
    }
}

// ============================================================================
// Kernel 1: XG[b,t,j] = Wih0[row_j]·x[b,t] + bih0[row_j] + bhh0[row_j],
// row_j = (j>>2) + 128*(j&3)  (unit j>>2, gate j&3); coalesced stores.
// ============================================================================
__global__ __launch_bounds__(512) void xg_precompute(
    const float* __restrict__ X, const float* __restrict__ Wih0,
    const float* __restrict__ bih0, const float* __restrict__ bhh0,
    float* __restrict__ XG)
{
    __shared__ float xs[16][DIN];
    const int blk = blockIdx.x;               // over B * (T/16)
    const int b   = blk / (TLEN / 16);
    const int tc  = blk % (TLEN / 16);
    const int j   = threadIdx.x;
    const int row = (j >> 2) + 128 * (j & 3);

    const float* xsrc = X + ((size_t)b * TLEN + (size_t)tc * 16) * DIN;
    for (int i = j; i < 16 * DIN; i += 512) ((float*)xs)[i] = xsrc[i];
    __syncthreads();

    f4 w[16];
    const f4* wp = (const f4*)(Wih0 + (size_t)row * DIN);
    #pragma unroll
    for (int i = 0; i < 16; ++i) w[i] = wp[i];
    const float bias = bih0[row] + bhh0[row];

    float* dst = XG + ((size_t)b * TLEN + (size_t)tc * 16) * 512 + j;
    #pragma unroll 4
    for (int t = 0; t < 16; ++t) {
        float acc = bias;
        const f4* xv = (const f4*)&xs[t][0];
        #pragma unroll
        for (int i = 0; i < 16; ++i) {
            f4 x4 = xv[i];
            acc += w[i][0] * x4[0] + w[i][1] * x4[1] + w[i][2] * x4[2] + w[i][3] * x4[3];
        }
        dst[(size_t)t * 512] = acc;
    }
}

// ============================================================================
// Kernel 2: persistent fused 2-layer LSTM, 1024 threads/block, 1 block/batch.
// Thread t0: unit rg = t0>>3, k-slice kg = t0&7 (16 h-elements each).
// Weight footprint: 3 matrices x 4 gates x 8 f16-pairs = 96 VGPRs -> fits the
// hard 128-VGPR cap of a 16-wave block (4 waves/SIMD), guaranteeing residency.
// Iter tt: layer0 -> h0(tt+1) from xg(tt+1), h0(tt);
//          layer1 -> h1(tt)   from h0(tt),  h1(tt-1).   ONE barrier/step.
// ============================================================================
__global__ __launch_bounds__(1024, 4) void lstm2_fused8(
    const float* __restrict__ XG,
    const float* __restrict__ Whh0,
    const float* __restrict__ Wih1, const float* __restrict__ Whh1,
    const float* __restrict__ bih1, const float* __restrict__ bhh1,
    float* __restrict__ Out)
{
    __shared__ alignas(16) _Float16 h0buf[2][HID];
    __shared__ alignas(16) _Float16 h1buf[2][HID];

    const int b  = blockIdx.x;
    const int t0 = threadIdx.x;
    const int rg = t0 >> 3;      // hidden unit 0..127
    const int kg = t0 & 7;       // k-slice 0..7 (16 elems)
    const int g  = kg & 3;       // gate injected by this lane (only when kg<4)

    // ---- weights -> registers (f16 pairs): 96 VGPRs ----
    h2 whh0[4][8], wih1[4][8], whh1[4][8];
    #pragma unroll
    for (int m = 0; m < 4; ++m) {
        const int row = rg + 128 * m;
        const float2* a = (const float2*)(Whh0 + (size_t)row * HID + kg * 16);
        const float2* c = (const float2*)(Wih1 + (size_t)row * HID + kg * 16);
        const float2* d = (const float2*)(Whh1 + (size_t)row * HID + kg * 16);
        #pragma unroll
        for (int i = 0; i < 8; ++i) {
            float2 v; h2 w;
            v = a[i]; w.x = (_Float16)v.x; w.y = (_Float16)v.y; whh0[m][i] = w;
            v = c[i]; w.x = (_Float16)v.x; w.y = (_Float16)v.y; wih1[m][i] = w;
            v = d[i]; w.x = (_Float16)v.x; w.y = (_Float16)v.y; whh1[m][i] = w;
        }
    }
    // layer-1 bias for the gate this lane injects (kg<4 lanes only inject)
    const float B1 = bih1[rg + 128 * g] + bhh1[rg + 128 * g];

    if (t0 < HID) {
        h0buf[0][t0] = (_Float16)0.0f; h0buf[1][t0] = (_Float16)0.0f;
        h1buf[0][t0] = (_Float16)0.0f; h1buf[1][t0] = (_Float16)0.0f;
    }
    __syncthreads();

    // this thread's xg stream: gate g of unit rg
    const float* xgp = XG + ((size_t)b * TLEN) * 512 + rg * 4 + g;
    float c0 = 0.0f, c1 = 0.0f;

    // ---- prologue: h0(0) from xg(0), h0(-1)=0 ----
    {
        float xg0 = xgp[0];
        float p[4];
        #pragma unroll
        for (int m = 0; m < 4; ++m) p[m] = (kg == m) ? xg0 : 0.0f;
        qreduce8(p);
        float ii = sigm(p[0]), gg = tanh_c(p[2]), oo = sigm(p[3]);
        c0 = ii * gg;
        if (kg == 0) h0buf[0][rg] = (_Float16)(oo * tanh_c(c0));
    }
    __syncthreads();

    float xg_next = xgp[512];    // xg(1), consumed at iter 0

    for (int tt = 0; tt < TLEN; ++tt) {
        const int cur = tt & 1, nxt = cur ^ 1;

        const float xgn = xg_next;                     // xg(tt+1)
        {
            const int tn = (tt + 2 < TLEN) ? tt + 2 : TLEN - 1;
            xg_next = xgp[(size_t)tn * 512];           // prefetch next iter's
        }

        float p[4], q[4];
        #pragma unroll
        for (int m = 0; m < 4; ++m) {
            p[m] = (kg == m) ? xgn : 0.0f;
            q[m] = (kg == m) ? B1  : 0.0f;
        }

        // this lane's 16-element slices of h0(tt) and h1(tt-1), in halves
        // (caps live h-temps at 8 dwords to protect the 128-VGPR budget)
        const uint4* H0 = (const uint4*)&h0buf[cur][kg * 16];
        const uint4* H1 = (const uint4*)&h1buf[cur][kg * 16];
        #pragma unroll
        for (int half = 0; half < 2; ++half) {
            u32 hw[4], gw[4];
            *(uint4*)&hw[0] = H0[half];
            *(uint4*)&gw[0] = H1[half];
            #pragma unroll
            for (int i4 = 0; i4 < 4; ++i4) {
                const int i = half * 4 + i4;
                const h2 hv = __builtin_bit_cast(h2, hw[i4]);
                const h2 gv = __builtin_bit_cast(h2, gw[i4]);
                #pragma unroll
                for (int m = 0; m < 4; ++m) {
                    p[m] = FDOT2(whh0[m][i], hv, p[m]);
                    q[m] = FDOT2(wih1[m][i], hv, q[m]);
                    q[m] = FDOT2(whh1[m][i], gv, q[m]);
                }
            }
        }

        qreduce8(p);
        qreduce8(q);

        // layer0 -> h0(tt+1)
        {
            float ii = sigm(p[0]), ff = sigm(p[1]);
            float gg = tanh_c(p[2]), oo = sigm(p[3]);
            c0 = ff * c0 + ii * gg;
            if (kg == 0) h0buf[nxt][rg] = (_Float16)(oo * tanh_c(c0));
        }
        // layer1 -> h1(tt)
        {
            float ii = sigm(q[0]), ff = sigm(q[1]);
            float gg = tanh_c(q[2]), oo = sigm(q[3]);
            c1 = ff * c1 + ii * gg;
            float h1v = oo * tanh_c(c1);
            if (kg == 0) {
                h1buf[nxt][rg] = (_Float16)h1v;
                Out[((size_t)b * TLEN + tt) * HID + rg] = h1v;
            }
        }
        __syncthreads();
    }
}

// ============================================================================
// Fallback (ws too small): round-1 kernel, known-correct at 6.8 ms.
// ============================================================================
__global__ __launch_bounds__(512, 2) void lstm2_persist(
    const float* __restrict__ X,
    const float* __restrict__ Wih0, const float* __restrict__ Whh0,
    const float* __restrict__ bih0, const float* __restrict__ bhh0,
    const float* __restrict__ Wih1, const float* __restrict__ Whh1,
    const float* __restrict__ bih1, const float* __restrict__ bhh1,
    float* __restrict__ Out)
{
    __shared__ unsigned int wih0_lds[512 * 33];
    __shared__ _Float16 h0buf[2][HID];
    __shared__ _Float16 h1buf[2][HID];

    const int b  = blockIdx.x;
    const int t  = threadIdx.x;
    const int rg = t >> 2;
    const int kg = t & 3;

    {
        const float2* src = (const float2*)(Wih0 + t * DIN);
        #pragma unroll
        for (int i = 0; i < 32; ++i) {
            float2 v = src[i];
            h2 p; p.x = (_Float16)v.x; p.y = (_Float16)v.y;
            wih0_lds[t * 33 + i] = __builtin_bit_cast(unsigned int, p);
        }
    }
    if (t < HID) {
        h0buf[0][t] = (_Float16)0.0f; h0buf[1][t] = (_Float16)0.0f;
        h1buf[0][t] = (_Float16)0.0f; h1buf[1][t] = (_Float16)0.0f;
    }

    h2 whh0[4][16], wih1[4][16], whh1[4][16];
    float bi0[4], bi1[4];
    #pragma unroll
    for (int m = 0; m < 4; ++m) {
        const int row = rg + 128 * m;
        const float2* a = (const float2*)(Whh0 + row * HID + kg * 32);
        const float2* c = (const float2*)(Wih1 + row * HID + kg * 32);
        const float2* d = (const float2*)(Whh1 + row * HID + kg * 32);
        #pragma unroll
        for (int i = 0; i < 16; ++i) {
            float2 v; h2 w;
            v = a[i]; w.x = (_Float16)v.x; w.y = (_Float16)v.y; whh0[m][i] = w;
            v = c[i]; w.x = (_Float16)v.x; w.y = (_Float16)v.y; wih1[m][i] = w;
            v = d[i]; w.x = (_Float16)v.x; w.y = (_Float16)v.y; whh1[m][i] = w;
        }
        bi0[m] = (kg == 0) ? (bih0[row] + bhh0[row]) : 0.0f;
        bi1[m] = (kg == 0) ? (bih1[row] + bhh1[row]) : 0.0f;
    }

    float c0 = 0.0f, c1 = 0.0f;
    __syncthreads();

    f4 xA[4], xB[4];
    {
        const f4* xp = (const f4*)(X + ((size_t)b * TLEN) * DIN + kg * 16);
        #pragma unroll
        for (int j = 0; j < 4; ++j) xA[j] = xp[j];
    }

    auto step = [&](int tt, f4 (&xc)[4], f4 (&xn)[4]) {
        const int cur = tt & 1, nxt = cur ^ 1;
        h2 xh[8];
        const float* xf = (const float*)xc;
        #pragma unroll
        for (int j = 0; j < 8; ++j) {
            h2 p; p.x = (_Float16)xf[2 * j]; p.y = (_Float16)xf[2 * j + 1];
            xh[j] = p;
        }
        {
            const int tn = (tt + 1 < TLEN) ? tt + 1 : TLEN - 1;
            const f4* xp = (const f4*)(X + ((size_t)b * TLEN + tn) * DIN + kg * 16);
            #pragma unroll
            for (int j = 0; j < 4; ++j) xn[j] = xp[j];
        }
        float p0[4];
        #pragma unroll
        for (int m = 0; m < 4; ++m) p0[m] = bi0[m];
        #pragma unroll
        for (int m = 0; m < 4; ++m) {
            const unsigned int* wr = &wih0_lds[(rg + 128 * m) * 33 + kg * 8];
            #pragma unroll
            for (int i = 0; i < 8; ++i) {
                h2 w = __builtin_bit_cast(h2, wr[i]);
                p0[m] = FDOT2(w, xh[i], p0[m]);
            }
        }
        {
            const unsigned int* hr = (const unsigned int*)&h0buf[cur][0];
            #pragma unroll
            for (int i = 0; i < 16; ++i) {
                h2 hv = __builtin_bit_cast(h2, hr[kg * 16 + i]);
                #pragma unroll
                for (int m = 0; m < 4; ++m)
                    p0[m] = FDOT2(whh0[m][i], hv, p0[m]);
            }
        }
        #pragma unroll
        for (int m = 0; m < 4; ++m) {
            p0[m] += __shfl_xor(p0[m], 1, 4);
            p0[m] += __shfl_xor(p0[m], 2, 4);
        }
        {
            float ii = sigm(p0[0]), ff = sigm(p0[1]);
            float gg = tanh_c(p0[2]), oo = sigm(p0[3]);
            c0 = ff * c0 + ii * gg;
            float h0v = oo * tanh_c(c0);
            if (kg == 0) h0buf[nxt][rg] = (_Float16)h0v;
        }
        __syncthreads();
        float q[4];
        #pragma unroll
        for (int m = 0; m < 4; ++m) q[m] = bi1[m];
        {
            const unsigned int* hr = (const unsigned int*)&h0buf[nxt][0];
            #pragma unroll
            for (int i = 0; i < 16; ++i) {
                h2 hv = __builtin_bit_cast(h2, hr[kg * 16 + i]);
                #pragma unroll
                for (int m = 0; m < 4; ++m)
                    q[m] = FDOT2(wih1[m][i], hv, q[m]);
            }
        }
        {
            const unsigned int* hr = (const unsigned int*)&h1buf[cur][0];
            #pragma unroll
            for (int i = 0; i < 16; ++i) {
                h2 hv = __builtin_bit_cast(h2, hr[kg * 16 + i]);
                #pragma unroll
                for (int m = 0; m < 4; ++m)
                    q[m] = FDOT2(whh1[m][i], hv, q[m]);
            }
        }
        #pragma unroll
        for (int m = 0; m < 4; ++m) {
            q[m] += __shfl_xor(q[m], 1, 4);
            q[m] += __shfl_xor(q[m], 2, 4);
        }
        {
            float ii = sigm(q[0]), ff = sigm(q[1]);
            float gg = tanh_c(q[2]), oo = sigm(q[3]);
            c1 = ff * c1 + ii * gg;
            float h1v = oo * tanh_c(c1);
            if (kg == 0) {
                h1buf[nxt][rg] = (_Float16)h1v;
                Out[((size_t)b * TLEN + tt) * HID + rg] = h1v;
            }
        }
        __syncthreads();
    };

    for (int tt = 0; tt < TLEN; tt += 2) {
        step(tt, xA, xB);
        step(tt + 1, xB, xA);
    }
}

extern "C" void kernel_launch(void* const* d_in, const int* in_sizes, int n_in,
                              void* d_out, int out_size, void* d_ws, size_t ws_size,
                              hipStream_t stream) {
    const float* X    = (const float*)d_in[0];
    const float* Wih0 = (const float*)d_in[1];
    const float* Whh0 = (const float*)d_in[2];
    const float* bih0 = (const float*)d_in[3];
    const float* bhh0 = (const float*)d_in[4];
    const float* Wih1 = (const float*)d_in[5];
    const float* Whh1 = (const float*)d_in[6];
    const float* bih1 = (const float*)d_in[7];
    const float* bhh1 = (const float*)d_in[8];
    float* Out = (float*)d_out;

    const size_t NG = (size_t)BATCH * TLEN * 512;        // xg element count
    if (ws_size >= NG * sizeof(float)) {
        float* XG = (float*)d_ws;
        xg_precompute<<<dim3(BATCH * (TLEN / 16)), dim3(512), 0, stream>>>(
            X, Wih0, bih0, bhh0, XG);
        lstm2_fused8<<<dim3(BATCH), dim3(1024), 0, stream>>>(
            XG, Whh0, Wih1, Whh1, bih1, bhh1, Out);
    } else {
        lstm2_persist<<<dim3(BATCH), dim3(512), 0, stream>>>(
            X, Wih0, Whh0, bih0, bhh0, Wih1, Whh1, bih1, bhh1, Out);
    }
}

// Round 5
// 3855.296 us; speedup vs baseline: 1.3985x; 1.3985x over previous
//
#include <hip/hip_runtime.h>

#define TLEN 2048
#define BATCH 32
#define DIN 64
#define HID 128

typedef _Float16 h2 __attribute__((ext_vector_type(2)));
typedef float f4 __attribute__((ext_vector_type(4)));
typedef unsigned int u32;

#if defined(__has_builtin)
#if __has_builtin(__builtin_amdgcn_fdot2)
#define FDOT2(a, b, c) __builtin_amdgcn_fdot2((a), (b), (c), false)
#endif
#endif
#ifndef FDOT2
#define FDOT2(a, b, c) ((c) + (float)(a).x * (float)(b).x + (float)(a).y * (float)(b).y)
#endif

__device__ __forceinline__ float sigm(float x) { return 1.0f / (1.0f + __expf(-x)); }
__device__ __forceinline__ float tanh_c(float x) {
    x = fminf(fmaxf(x, -15.0f), 15.0f);
    float e = __expf(2.0f * x);
    return (e - 1.0f) / (e + 1.0f);
}

// quad butterfly (R1/R3-proven __shfl_xor idiom, width 4)
__device__ __forceinline__ void qreduce(float (&v)[4]) {
    #pragma unroll
    for (int m = 0; m < 4; ++m) {
        v[m] += __shfl_xor(v[m], 1, 4);
        v[m] += __shfl_xor(v[m], 2, 4);
    }
}

// ============================================================================
// Kernel 1: XG[b,t,j] = Wih0[row_j]·x[b,t] + bih0[row_j] + bhh0[row_j],
// row_j = (j>>2) + 128*(j&3)  (unit j>>2, gate j&3); coalesced stores.
// ============================================================================
template <typename XT>
__global__ __launch_bounds__(512) void xg_precompute(
    const float* __restrict__ X, const float* __restrict__ Wih0,
    const float* __restrict__ bih0, const float* __restrict__ bhh0,
    XT* __restrict__ XG)
{
    __shared__ float xs[16][DIN];
    const int blk = blockIdx.x;               // over B * (T/16)
    const int b   = blk / (TLEN / 16);
    const int tc  = blk % (TLEN / 16);
    const int j   = threadIdx.x;
    const int row = (j >> 2) + 128 * (j & 3);

    const float* xsrc = X + ((size_t)b * TLEN + (size_t)tc * 16) * DIN;
    for (int i = j; i < 16 * DIN; i += 512) ((float*)xs)[i] = xsrc[i];
    __syncthreads();

    f4 w[16];
    const f4* wp = (const f4*)(Wih0 + (size_t)row * DIN);
    #pragma unroll
    for (int i = 0; i < 16; ++i) w[i] = wp[i];
    const float bias = bih0[row] + bhh0[row];

    XT* dst = XG + ((size_t)b * TLEN + (size_t)tc * 16) * 512 + j;
    #pragma unroll 4
    for (int t = 0; t < 16; ++t) {
        float acc = bias;
        const f4* xv = (const f4*)&xs[t][0];
        #pragma unroll
        for (int i = 0; i < 16; ++i) {
            f4 x4 = xv[i];
            acc += w[i][0] * x4[0] + w[i][1] * x4[1] + w[i][2] * x4[2] + w[i][3] * x4[3];
        }
        dst[(size_t)t * 512] = (XT)acc;
    }
}

// ============================================================================
// Kernel 2: persistent fused 2-layer LSTM, one block per batch element.
// Thread t0: unit rg = t0>>2, k-slice kg = t0&3 (32 h-elements each).
// __launch_bounds__(512, 1): arg2 is CUDA-style min BLOCKS/CU on this
// toolchain (R1/R3 observed cap 128 at (512,2); R4 observed 64 at (1024,4))
// -> 1 block x 8 waves = 2 waves/SIMD -> 256-VGPR cap; weight demand ~230
// dwords finally fits, making the 192-dword f16 weight set register-resident.
// Iter tt: layer0 -> h0(tt+1) from xg(tt+1), h0(tt);
//          layer1 -> h1(tt)   from h0(tt),  h1(tt-1).   ONE barrier/step.
// ============================================================================
template <typename XT>
__global__ __launch_bounds__(512, 1) void lstm2_fused(
    const XT* __restrict__ XG,
    const float* __restrict__ Whh0,
    const float* __restrict__ Wih1, const float* __restrict__ Whh1,
    const float* __restrict__ bih1, const float* __restrict__ bhh1,
    float* __restrict__ Out)
{
    __shared__ alignas(16) _Float16 h0buf[2][HID];
    __shared__ alignas(16) _Float16 h1buf[2][HID];

    const int b  = blockIdx.x;
    const int t0 = threadIdx.x;
    const int rg = t0 >> 2;
    const int kg = t0 & 3;

    // weights -> registers (f16 pairs): 192 VGPRs
    h2 whh0[4][16], wih1[4][16], whh1[4][16];
    #pragma unroll
    for (int m = 0; m < 4; ++m) {
        const int row = rg + 128 * m;
        const float2* a = (const float2*)(Whh0 + (size_t)row * HID + kg * 32);
        const float2* c = (const float2*)(Wih1 + (size_t)row * HID + kg * 32);
        const float2* d = (const float2*)(Whh1 + (size_t)row * HID + kg * 32);
        #pragma unroll
        for (int i = 0; i < 16; ++i) {
            float2 v; h2 w;
            v = a[i]; w.x = (_Float16)v.x; w.y = (_Float16)v.y; whh0[m][i] = w;
            v = c[i]; w.x = (_Float16)v.x; w.y = (_Float16)v.y; wih1[m][i] = w;
            v = d[i]; w.x = (_Float16)v.x; w.y = (_Float16)v.y; whh1[m][i] = w;
        }
    }

    // layer-1 bias for the gate this lane injects (gate index == kg)
    const float B1 = bih1[rg + 128 * kg] + bhh1[rg + 128 * kg];

    if (t0 < HID) {
        h0buf[0][t0] = (_Float16)0.0f; h0buf[1][t0] = (_Float16)0.0f;
        h1buf[0][t0] = (_Float16)0.0f; h1buf[1][t0] = (_Float16)0.0f;
    }
    __syncthreads();

    const XT* xgp = XG + ((size_t)b * TLEN) * 512 + t0;
    float c0 = 0.0f, c1 = 0.0f;

    // prologue: h0(0) from xg(0), h0(-1)=0
    {
        float xg0 = (float)xgp[0];
        float p[4];
        #pragma unroll
        for (int m = 0; m < 4; ++m) p[m] = (kg == m) ? xg0 : 0.0f;
        qreduce(p);
        float ii = sigm(p[0]), gg = tanh_c(p[2]), oo = sigm(p[3]);
        c0 = ii * gg;
        if (kg == 0) h0buf[0][rg] = (_Float16)(oo * tanh_c(c0));
    }
    __syncthreads();

    // xg prefetch ring (depth 2)
    float xg_next = (float)xgp[512];          // xg(1), used at iter 0
    XT    xg_pend = xgp[2 * 512];             // xg(2), used at iter 1

    for (int tt = 0; tt < TLEN; ++tt) {
        const int cur = tt & 1, nxt = cur ^ 1;

        const float xgn = xg_next;            // xg(tt+1)
        xg_next = (float)xg_pend;
        {
            const int tnn = (tt + 3 < TLEN) ? tt + 3 : TLEN - 1;
            xg_pend = xgp[(size_t)tnn * 512];
        }

        float p[4], q[4];
        #pragma unroll
        for (int m = 0; m < 4; ++m) {
            p[m] = (kg == m) ? xgn : 0.0f;
            q[m] = (kg == m) ? B1  : 0.0f;
        }

        // this lane's 32-element slices of h0(tt) and h1(tt-1): 4 b128 each,
        // broadcast addresses (4 distinct per wave) -> conflict-free
        const uint4* H0 = (const uint4*)&h0buf[cur][kg * 32];
        const uint4* H1 = (const uint4*)&h1buf[cur][kg * 32];
        #pragma unroll
        for (int qr = 0; qr < 4; ++qr) {
            u32 hw[4], gw[4];
            *(uint4*)&hw[0] = H0[qr];
            *(uint4*)&gw[0] = H1[qr];
            #pragma unroll
            for (int w = 0; w < 4; ++w) {
                const int i = qr * 4 + w;    // pair index 0..15
                const h2 hv = __builtin_bit_cast(h2, hw[w]);
                const h2 gv = __builtin_bit_cast(h2, gw[w]);
                #pragma unroll
                for (int m = 0; m < 4; ++m) {
                    p[m] = FDOT2(whh0[m][i], hv, p[m]);
                    q[m] = FDOT2(wih1[m][i], hv, q[m]);
                    q[m] = FDOT2(whh1[m][i], gv, q[m]);
                }
            }
        }

        qreduce(p);
        qreduce(q);

        // layer0 -> h0(tt+1)
        {
            float ii = sigm(p[0]), ff = sigm(p[1]);
            float gg = tanh_c(p[2]), oo = sigm(p[3]);
            c0 = ff * c0 + ii * gg;
            if (kg == 0) h0buf[nxt][rg] = (_Float16)(oo * tanh_c(c0));
        }
        // layer1 -> h1(tt)
        {
            float ii = sigm(q[0]), ff = sigm(q[1]);
            float gg = tanh_c(q[2]), oo = sigm(q[3]);
            c1 = ff * c1 + ii * gg;
            float h1v = oo * tanh_c(c1);
            if (kg == 0) {
                h1buf[nxt][rg] = (_Float16)h1v;
                Out[((size_t)b * TLEN + tt) * HID + rg] = h1v;
            }
        }
        __syncthreads();
    }
}

// ============================================================================
// Fallback (ws too small): round-1 kernel, known-correct at 6.8 ms.
// ============================================================================
__global__ __launch_bounds__(512, 2) void lstm2_persist(
    const float* __restrict__ X,
    const float* __restrict__ Wih0, const float* __restrict__ Whh0,
    const float* __restrict__ bih0, const float* __restrict__ bhh0,
    const float* __restrict__ Wih1, const float* __restrict__ Whh1,
    const float* __restrict__ bih1, const float* __restrict__ bhh1,
    float* __restrict__ Out)
{
    __shared__ unsigned int wih0_lds[512 * 33];
    __shared__ _Float16 h0buf[2][HID];
    __shared__ _Float16 h1buf[2][HID];

    const int b  = blockIdx.x;
    const int t  = threadIdx.x;
    const int rg = t >> 2;
    const int kg = t & 3;

    {
        const float2* src = (const float2*)(Wih0 + t * DIN);
        #pragma unroll
        for (int i = 0; i < 32; ++i) {
            float2 v = src[i];
            h2 p; p.x = (_Float16)v.x; p.y = (_Float16)v.y;
            wih0_lds[t * 33 + i] = __builtin_bit_cast(unsigned int, p);
        }
    }
    if (t < HID) {
        h0buf[0][t] = (_Float16)0.0f; h0buf[1][t] = (_Float16)0.0f;
        h1buf[0][t] = (_Float16)0.0f; h1buf[1][t] = (_Float16)0.0f;
    }

    h2 whh0[4][16], wih1[4][16], whh1[4][16];
    float bi0[4], bi1[4];
    #pragma unroll
    for (int m = 0; m < 4; ++m) {
        const int row = rg + 128 * m;
        const float2* a = (const float2*)(Whh0 + row * HID + kg * 32);
        const float2* c = (const float2*)(Wih1 + row * HID + kg * 32);
        const float2* d = (const float2*)(Whh1 + row * HID + kg * 32);
        #pragma unroll
        for (int i = 0; i < 16; ++i) {
            float2 v; h2 w;
            v = a[i]; w.x = (_Float16)v.x; w.y = (_Float16)v.y; whh0[m][i] = w;
            v = c[i]; w.x = (_Float16)v.x; w.y = (_Float16)v.y; wih1[m][i] = w;
            v = d[i]; w.x = (_Float16)v.x; w.y = (_Float16)v.y; whh1[m][i] = w;
        }
        bi0[m] = (kg == 0) ? (bih0[row] + bhh0[row]) : 0.0f;
        bi1[m] = (kg == 0) ? (bih1[row] + bhh1[row]) : 0.0f;
    }

    float c0 = 0.0f, c1 = 0.0f;
    __syncthreads();

    f4 xA[4], xB[4];
    {
        const f4* xp = (const f4*)(X + ((size_t)b * TLEN) * DIN + kg * 16);
        #pragma unroll
        for (int j = 0; j < 4; ++j) xA[j] = xp[j];
    }

    auto step = [&](int tt, f4 (&xc)[4], f4 (&xn)[4]) {
        const int cur = tt & 1, nxt = cur ^ 1;
        h2 xh[8];
        const float* xf = (const float*)xc;
        #pragma unroll
        for (int j = 0; j < 8; ++j) {
            h2 p; p.x = (_Float16)xf[2 * j]; p.y = (_Float16)xf[2 * j + 1];
            xh[j] = p;
        }
        {
            const int tn = (tt + 1 < TLEN) ? tt + 1 : TLEN - 1;
            const f4* xp = (const f4*)(X + ((size_t)b * TLEN + tn) * DIN + kg * 16);
            #pragma unroll
            for (int j = 0; j < 4; ++j) xn[j] = xp[j];
        }
        float p0[4];
        #pragma unroll
        for (int m = 0; m < 4; ++m) p0[m] = bi0[m];
        #pragma unroll
        for (int m = 0; m < 4; ++m) {
            const unsigned int* wr = &wih0_lds[(rg + 128 * m) * 33 + kg * 8];
            #pragma unroll
            for (int i = 0; i < 8; ++i) {
                h2 w = __builtin_bit_cast(h2, wr[i]);
                p0[m] = FDOT2(w, xh[i], p0[m]);
            }
        }
        {
            const unsigned int* hr = (const unsigned int*)&h0buf[cur][0];
            #pragma unroll
            for (int i = 0; i < 16; ++i) {
                h2 hv = __builtin_bit_cast(h2, hr[kg * 16 + i]);
                #pragma unroll
                for (int m = 0; m < 4; ++m)
                    p0[m] = FDOT2(whh0[m][i], hv, p0[m]);
            }
        }
        #pragma unroll
        for (int m = 0; m < 4; ++m) {
            p0[m] += __shfl_xor(p0[m], 1, 4);
            p0[m] += __shfl_xor(p0[m], 2, 4);
        }
        {
            float ii = sigm(p0[0]), ff = sigm(p0[1]);
            float gg = tanh_c(p0[2]), oo = sigm(p0[3]);
            c0 = ff * c0 + ii * gg;
            float h0v = oo * tanh_c(c0);
            if (kg == 0) h0buf[nxt][rg] = (_Float16)h0v;
        }
        __syncthreads();
        float q[4];
        #pragma unroll
        for (int m = 0; m < 4; ++m) q[m] = bi1[m];
        {
            const unsigned int* hr = (const unsigned int*)&h0buf[nxt][0];
            #pragma unroll
            for (int i = 0; i < 16; ++i) {
                h2 hv = __builtin_bit_cast(h2, hr[kg * 16 + i]);
                #pragma unroll
                for (int m = 0; m < 4; ++m)
                    q[m] = FDOT2(wih1[m][i], hv, q[m]);
            }
        }
        {
            const unsigned int* hr = (const unsigned int*)&h1buf[cur][0];
            #pragma unroll
            for (int i = 0; i < 16; ++i) {
                h2 hv = __builtin_bit_cast(h2, hr[kg * 16 + i]);
                #pragma unroll
                for (int m = 0; m < 4; ++m)
                    q[m] = FDOT2(whh1[m][i], hv, q[m]);
            }
        }
        #pragma unroll
        for (int m = 0; m < 4; ++m) {
            q[m] += __shfl_xor(q[m], 1, 4);
            q[m] += __shfl_xor(q[m], 2, 4);
        }
        {
            float ii = sigm(q[0]), ff = sigm(q[1]);
            float gg = tanh_c(q[2]), oo = sigm(q[3]);
            c1 = ff * c1 + ii * gg;
            float h1v = oo * tanh_c(c1);
            if (kg == 0) {
                h1buf[nxt][rg] = (_Float16)h1v;
                Out[((size_t)b * TLEN + tt) * HID + rg] = h1v;
            }
        }
        __syncthreads();
    };

    for (int tt = 0; tt < TLEN; tt += 2) {
        step(tt, xA, xB);
        step(tt + 1, xB, xA);
    }
}

extern "C" void kernel_launch(void* const* d_in, const int* in_sizes, int n_in,
                              void* d_out, int out_size, void* d_ws, size_t ws_size,
                              hipStream_t stream) {
    const float* X    = (const float*)d_in[0];
    const float* Wih0 = (const float*)d_in[1];
    const float* Whh0 = (const float*)d_in[2];
    const float* bih0 = (const float*)d_in[3];
    const float* bhh0 = (const float*)d_in[4];
    const float* Wih1 = (const float*)d_in[5];
    const float* Whh1 = (const float*)d_in[6];
    const float* bih1 = (const float*)d_in[7];
    const float* bhh1 = (const float*)d_in[8];
    float* Out = (float*)d_out;

    const size_t NG = (size_t)BATCH * TLEN * 512;        // xg element count
    if (ws_size >= NG * sizeof(float)) {
        float* XG = (float*)d_ws;
        xg_precompute<float><<<dim3(BATCH * (TLEN / 16)), dim3(512), 0, stream>>>(
            X, Wih0, bih0, bhh0, XG);
        lstm2_fused<float><<<dim3(BATCH), dim3(512), 0, stream>>>(
            XG, Whh0, Wih1, Whh1, bih1, bhh1, Out);
    } else if (ws_size >= NG * sizeof(_Float16)) {
        _Float16* XG = (_Float16*)d_ws;
        xg_precompute<_Float16><<<dim3(BATCH * (TLEN / 16)), dim3(512), 0, stream>>>(
            X, Wih0, bih0, bhh0, XG);
        lstm2_fused<_Float16><<<dim3(BATCH), dim3(512), 0, stream>>>(
            XG, Whh0, Wih1, Whh1, bih1, bhh1, Out);
    } else {
        lstm2_persist<<<dim3(BATCH), dim3(512), 0, stream>>>(
            X, Wih0, Whh0, bih0, bhh0, Wih1, Whh1, bih1, bhh1, Out);
    }
}

// Round 6
// 3851.840 us; speedup vs baseline: 1.3997x; 1.0009x over previous
//
#include <hip/hip_runtime.h>

#define TLEN 2048
#define BATCH 32
#define DIN 64
#define HID 128

typedef _Float16 h2 __attribute__((ext_vector_type(2)));
typedef float f4 __attribute__((ext_vector_type(4)));
typedef unsigned int u32;

#if defined(__has_builtin)
#if __has_builtin(__builtin_amdgcn_fdot2)
#define FDOT2(a, b, c) __builtin_amdgcn_fdot2((a), (b), (c), false)
#endif
#endif
#ifndef FDOT2
#define FDOT2(a, b, c) ((c) + (float)(a).x * (float)(b).x + (float)(a).y * (float)(b).y)
#endif

#define DOT2U(wu, hv, acc) FDOT2(__builtin_bit_cast(h2, (wu)), (hv), (acc))

__device__ __forceinline__ float sigm(float x) { return 1.0f / (1.0f + __expf(-x)); }
__device__ __forceinline__ float tanh_c(float x) {
    x = fminf(fmaxf(x, -15.0f), 15.0f);
    float e = __expf(2.0f * x);
    return (e - 1.0f) / (e + 1.0f);
}

// quad butterfly (R1/R3/R5-proven __shfl_xor idiom, width 4)
__device__ __forceinline__ void qreduce(float (&v)[4]) {
    #pragma unroll
    for (int m = 0; m < 4; ++m) {
        v[m] += __shfl_xor(v[m], 1, 4);
        v[m] += __shfl_xor(v[m], 2, 4);
    }
}

// ============================================================================
// Kernel 1: XG[b,t,j] = Wih0[row_j]·x[b,t] + bih0[row_j] + bhh0[row_j],
// row_j = (j>>2) + 128*(j&3)  (unit j>>2, gate j&3); coalesced stores.
// ============================================================================
template <typename XT>
__global__ __launch_bounds__(512) void xg_precompute(
    const float* __restrict__ X, const float* __restrict__ Wih0,
    const float* __restrict__ bih0, const float* __restrict__ bhh0,
    XT* __restrict__ XG)
{
    __shared__ float xs[16][DIN];
    const int blk = blockIdx.x;               // over B * (T/16)
    const int b   = blk / (TLEN / 16);
    const int tc  = blk % (TLEN / 16);
    const int j   = threadIdx.x;
    const int row = (j >> 2) + 128 * (j & 3);

    const float* xsrc = X + ((size_t)b * TLEN + (size_t)tc * 16) * DIN;
    for (int i = j; i < 16 * DIN; i += 512) ((float*)xs)[i] = xsrc[i];
    __syncthreads();

    f4 w[16];
    const f4* wp = (const f4*)(Wih0 + (size_t)row * DIN);
    #pragma unroll
    for (int i = 0; i < 16; ++i) w[i] = wp[i];
    const float bias = bih0[row] + bhh0[row];

    XT* dst = XG + ((size_t)b * TLEN + (size_t)tc * 16) * 512 + j;
    #pragma unroll 4
    for (int t = 0; t < 16; ++t) {
        float acc = bias;
        const f4* xv = (const f4*)&xs[t][0];
        #pragma unroll
        for (int i = 0; i < 16; ++i) {
            f4 x4 = xv[i];
            acc += w[i][0] * x4[0] + w[i][1] * x4[1] + w[i][2] * x4[2] + w[i][3] * x4[3];
        }
        dst[(size_t)t * 512] = (XT)acc;
    }
}

// ============================================================================
// Kernel 2: persistent fused 2-layer LSTM, one block per batch element.
// Thread t0: unit rg = t0>>2, k-slice kg = t0&3 (32 h-elements each).
//
// Register residency, forced two ways (R3/R4/R5 showed launch_bounds alone
// cannot raise the allocator's 128-VGPR heuristic cap):
//  (1) amdgpu_waves_per_eu(2,2): backend budget = 512/2 = 256 VGPRs, still
//      launchable for an 8-wave block (2 waves/SIMD) and free at 32 blocks.
//  (2) asm volatile("" : "+v"(w)) pins on every weight dword: opaque VGPR
//      defs the scheduler can neither rematerialize nor sink into the loop.
//
// Iter tt: layer0 -> h0(tt+1) from xg(tt+1), h0(tt);
//          layer1 -> h1(tt)   from h0(tt),  h1(tt-1).   ONE barrier/step.
// ============================================================================
template <typename XT>
__global__ __attribute__((amdgpu_flat_work_group_size(512, 512),
                          amdgpu_waves_per_eu(2, 2)))
void lstm2_fused(
    const XT* __restrict__ XG,
    const float* __restrict__ Whh0,
    const float* __restrict__ Wih1, const float* __restrict__ Whh1,
    const float* __restrict__ bih1, const float* __restrict__ bhh1,
    float* __restrict__ Out)
{
    __shared__ alignas(16) _Float16 h0buf[2][HID];
    __shared__ alignas(16) _Float16 h1buf[2][HID];

    const int b  = blockIdx.x;
    const int t0 = threadIdx.x;
    const int rg = t0 >> 2;
    const int kg = t0 & 3;

    // ---- weights -> registers as raw u32 (f16 pairs): 192 VGPRs ----
    u32 whh0u[4][16], wih1u[4][16], whh1u[4][16];
    #pragma unroll
    for (int m = 0; m < 4; ++m) {
        const int row = rg + 128 * m;
        const float2* a = (const float2*)(Whh0 + (size_t)row * HID + kg * 32);
        const float2* c = (const float2*)(Wih1 + (size_t)row * HID + kg * 32);
        const float2* d = (const float2*)(Whh1 + (size_t)row * HID + kg * 32);
        #pragma unroll
        for (int i = 0; i < 16; ++i) {
            float2 v; h2 w;
            v = a[i]; w.x = (_Float16)v.x; w.y = (_Float16)v.y;
            whh0u[m][i] = __builtin_bit_cast(u32, w);
            v = c[i]; w.x = (_Float16)v.x; w.y = (_Float16)v.y;
            wih1u[m][i] = __builtin_bit_cast(u32, w);
            v = d[i]; w.x = (_Float16)v.x; w.y = (_Float16)v.y;
            whh1u[m][i] = __builtin_bit_cast(u32, w);
        }
    }
    // pin: force all 192 weight dwords live in VGPRs; block remat/sinking
    #pragma unroll
    for (int m = 0; m < 4; ++m) {
        #pragma unroll
        for (int i = 0; i < 16; ++i) {
            asm volatile("" : "+v"(whh0u[m][i]));
            asm volatile("" : "+v"(wih1u[m][i]));
            asm volatile("" : "+v"(whh1u[m][i]));
        }
    }

    // layer-1 bias for the gate this lane injects (gate index == kg)
    const float B1 = bih1[rg + 128 * kg] + bhh1[rg + 128 * kg];

    if (t0 < HID) {
        h0buf[0][t0] = (_Float16)0.0f; h0buf[1][t0] = (_Float16)0.0f;
        h1buf[0][t0] = (_Float16)0.0f; h1buf[1][t0] = (_Float16)0.0f;
    }
    __syncthreads();

    const XT* xgp = XG + ((size_t)b * TLEN) * 512 + t0;
    float c0 = 0.0f, c1 = 0.0f;

    // prologue: h0(0) from xg(0), h0(-1)=0
    {
        float xg0 = (float)xgp[0];
        float p[4];
        #pragma unroll
        for (int m = 0; m < 4; ++m) p[m] = (kg == m) ? xg0 : 0.0f;
        qreduce(p);
        float ii = sigm(p[0]), gg = tanh_c(p[2]), oo = sigm(p[3]);
        c0 = ii * gg;
        if (kg == 0) h0buf[0][rg] = (_Float16)(oo * tanh_c(c0));
    }
    __syncthreads();

    // xg prefetch ring (depth 2)
    float xg_next = (float)xgp[512];          // xg(1), used at iter 0
    XT    xg_pend = xgp[2 * 512];             // xg(2), used at iter 1

    for (int tt = 0; tt < TLEN; ++tt) {
        const int cur = tt & 1, nxt = cur ^ 1;

        const float xgn = xg_next;            // xg(tt+1)
        xg_next = (float)xg_pend;
        {
            const int tnn = (tt + 3 < TLEN) ? tt + 3 : TLEN - 1;
            xg_pend = xgp[(size_t)tnn * 512];
        }

        float p[4], q[4];
        #pragma unroll
        for (int m = 0; m < 4; ++m) {
            p[m] = (kg == m) ? xgn : 0.0f;
            q[m] = (kg == m) ? B1  : 0.0f;
        }

        // this lane's 32-element slices of h0(tt) and h1(tt-1): 4 b128 each,
        // broadcast addresses (4 distinct per wave) -> conflict-free
        const uint4* H0 = (const uint4*)&h0buf[cur][kg * 32];
        const uint4* H1 = (const uint4*)&h1buf[cur][kg * 32];
        #pragma unroll
        for (int qr = 0; qr < 4; ++qr) {
            u32 hw[4], gw[4];
            *(uint4*)&hw[0] = H0[qr];
            *(uint4*)&gw[0] = H1[qr];
            #pragma unroll
            for (int w = 0; w < 4; ++w) {
                const int i = qr * 4 + w;    // pair index 0..15
                const h2 hv = __builtin_bit_cast(h2, hw[w]);
                const h2 gv = __builtin_bit_cast(h2, gw[w]);
                #pragma unroll
                for (int m = 0; m < 4; ++m) {
                    p[m] = DOT2U(whh0u[m][i], hv, p[m]);
                    q[m] = DOT2U(wih1u[m][i], hv, q[m]);
                    q[m] = DOT2U(whh1u[m][i], gv, q[m]);
                }
            }
        }

        qreduce(p);
        qreduce(q);

        // layer0 -> h0(tt+1)
        {
            float ii = sigm(p[0]), ff = sigm(p[1]);
            float gg = tanh_c(p[2]), oo = sigm(p[3]);
            c0 = ff * c0 + ii * gg;
            if (kg == 0) h0buf[nxt][rg] = (_Float16)(oo * tanh_c(c0));
        }
        // layer1 -> h1(tt)
        {
            float ii = sigm(q[0]), ff = sigm(q[1]);
            float gg = tanh_c(q[2]), oo = sigm(q[3]);
            c1 = ff * c1 + ii * gg;
            float h1v = oo * tanh_c(c1);
            if (kg == 0) {
                h1buf[nxt][rg] = (_Float16)h1v;
                Out[((size_t)b * TLEN + tt) * HID + rg] = h1v;
            }
        }
        __syncthreads();
    }
}

// ============================================================================
// Fallback (ws too small): round-1 kernel, known-correct at 6.8 ms.
// ============================================================================
__global__ __launch_bounds__(512, 2) void lstm2_persist(
    const float* __restrict__ X,
    const float* __restrict__ Wih0, const float* __restrict__ Whh0,
    const float* __restrict__ bih0, const float* __restrict__ bhh0,
    const float* __restrict__ Wih1, const float* __restrict__ Whh1,
    const float* __restrict__ bih1, const float* __restrict__ bhh1,
    float* __restrict__ Out)
{
    __shared__ unsigned int wih0_lds[512 * 33];
    __shared__ _Float16 h0buf[2][HID];
    __shared__ _Float16 h1buf[2][HID];

    const int b  = blockIdx.x;
    const int t  = threadIdx.x;
    const int rg = t >> 2;
    const int kg = t & 3;

    {
        const float2* src = (const float2*)(Wih0 + t * DIN);
        #pragma unroll
        for (int i = 0; i < 32; ++i) {
            float2 v = src[i];
            h2 p; p.x = (_Float16)v.x; p.y = (_Float16)v.y;
            wih0_lds[t * 33 + i] = __builtin_bit_cast(unsigned int, p);
        }
    }
    if (t < HID) {
        h0buf[0][t] = (_Float16)0.0f; h0buf[1][t] = (_Float16)0.0f;
        h1buf[0][t] = (_Float16)0.0f; h1buf[1][t] = (_Float16)0.0f;
    }

    h2 whh0[4][16], wih1[4][16], whh1[4][16];
    float bi0[4], bi1[4];
    #pragma unroll
    for (int m = 0; m < 4; ++m) {
        const int row = rg + 128 * m;
        const float2* a = (const float2*)(Whh0 + row * HID + kg * 32);
        const float2* c = (const float2*)(Wih1 + row * HID + kg * 32);
        const float2* d = (const float2*)(Whh1 + row * HID + kg * 32);
        #pragma unroll
        for (int i = 0; i < 16; ++i) {
            float2 v; h2 w;
            v = a[i]; w.x = (_Float16)v.x; w.y = (_Float16)v.y; whh0[m][i] = w;
            v = c[i]; w.x = (_Float16)v.x; w.y = (_Float16)v.y; wih1[m][i] = w;
            v = d[i]; w.x = (_Float16)v.x; w.y = (_Float16)v.y; whh1[m][i] = w;
        }
        bi0[m] = (kg == 0) ? (bih0[row] + bhh0[row]) : 0.0f;
        bi1[m] = (kg == 0) ? (bih1[row] + bhh1[row]) : 0.0f;
    }

    float c0 = 0.0f, c1 = 0.0f;
    __syncthreads();

    f4 xA[4], xB[4];
    {
        const f4* xp = (const f4*)(X + ((size_t)b * TLEN) * DIN + kg * 16);
        #pragma unroll
        for (int j = 0; j < 4; ++j) xA[j] = xp[j];
    }

    auto step = [&](int tt, f4 (&xc)[4], f4 (&xn)[4]) {
        const int cur = tt & 1, nxt = cur ^ 1;
        h2 xh[8];
        const float* xf = (const float*)xc;
        #pragma unroll
        for (int j = 0; j < 8; ++j) {
            h2 p; p.x = (_Float16)xf[2 * j]; p.y = (_Float16)xf[2 * j + 1];
            xh[j] = p;
        }
        {
            const int tn = (tt + 1 < TLEN) ? tt + 1 : TLEN - 1;
            const f4* xp = (const f4*)(X + ((size_t)b * TLEN + tn) * DIN + kg * 16);
            #pragma unroll
            for (int j = 0; j < 4; ++j) xn[j] = xp[j];
        }
        float p0[4];
        #pragma unroll
        for (int m = 0; m < 4; ++m) p0[m] = bi0[m];
        #pragma unroll
        for (int m = 0; m < 4; ++m) {
            const unsigned int* wr = &wih0_lds[(rg + 128 * m) * 33 + kg * 8];
            #pragma unroll
            for (int i = 0; i < 8; ++i) {
                h2 w = __builtin_bit_cast(h2, wr[i]);
                p0[m] = FDOT2(w, xh[i], p0[m]);
            }
        }
        {
            const unsigned int* hr = (const unsigned int*)&h0buf[cur][0];
            #pragma unroll
            for (int i = 0; i < 16; ++i) {
                h2 hv = __builtin_bit_cast(h2, hr[kg * 16 + i]);
                #pragma unroll
                for (int m = 0; m < 4; ++m)
                    p0[m] = FDOT2(whh0[m][i], hv, p0[m]);
            }
        }
        #pragma unroll
        for (int m = 0; m < 4; ++m) {
            p0[m] += __shfl_xor(p0[m], 1, 4);
            p0[m] += __shfl_xor(p0[m], 2, 4);
        }
        {
            float ii = sigm(p0[0]), ff = sigm(p0[1]);
            float gg = tanh_c(p0[2]), oo = sigm(p0[3]);
            c0 = ff * c0 + ii * gg;
            float h0v = oo * tanh_c(c0);
            if (kg == 0) h0buf[nxt][rg] = (_Float16)h0v;
        }
        __syncthreads();
        float q[4];
        #pragma unroll
        for (int m = 0; m < 4; ++m) q[m] = bi1[m];
        {
            const unsigned int* hr = (const unsigned int*)&h0buf[nxt][0];
            #pragma unroll
            for (int i = 0; i < 16; ++i) {
                h2 hv = __builtin_bit_cast(h2, hr[kg * 16 + i]);
                #pragma unroll
                for (int m = 0; m < 4; ++m)
                    q[m] = FDOT2(wih1[m][i], hv, q[m]);
            }
        }
        {
            const unsigned int* hr = (const unsigned int*)&h1buf[cur][0];
            #pragma unroll
            for (int i = 0; i < 16; ++i) {
                h2 hv = __builtin_bit_cast(h2, hr[kg * 16 + i]);
                #pragma unroll
                for (int m = 0; m < 4; ++m)
                    q[m] = FDOT2(whh1[m][i], hv, q[m]);
            }
        }
        #pragma unroll
        for (int m = 0; m < 4; ++m) {
            q[m] += __shfl_xor(q[m], 1, 4);
            q[m] += __shfl_xor(q[m], 2, 4);
        }
        {
            float ii = sigm(q[0]), ff = sigm(q[1]);
            float gg = tanh_c(q[2]), oo = sigm(q[3]);
            c1 = ff * c1 + ii * gg;
            float h1v = oo * tanh_c(c1);
            if (kg == 0) {
                h1buf[nxt][rg] = (_Float16)h1v;
                Out[((size_t)b * TLEN + tt) * HID + rg] = h1v;
            }
        }
        __syncthreads();
    };

    for (int tt = 0; tt < TLEN; tt += 2) {
        step(tt, xA, xB);
        step(tt + 1, xB, xA);
    }
}

extern "C" void kernel_launch(void* const* d_in, const int* in_sizes, int n_in,
                              void* d_out, int out_size, void* d_ws, size_t ws_size,
                              hipStream_t stream) {
    const float* X    = (const float*)d_in[0];
    const float* Wih0 = (const float*)d_in[1];
    const float* Whh0 = (const float*)d_in[2];
    const float* bih0 = (const float*)d_in[3];
    const float* bhh0 = (const float*)d_in[4];
    const float* Wih1 = (const float*)d_in[5];
    const float* Whh1 = (const float*)d_in[6];
    const float* bih1 = (const float*)d_in[7];
    const float* bhh1 = (const float*)d_in[8];
    float* Out = (float*)d_out;

    const size_t NG = (size_t)BATCH * TLEN * 512;        // xg element count
    if (ws_size >= NG * sizeof(float)) {
        float* XG = (float*)d_ws;
        xg_precompute<float><<<dim3(BATCH * (TLEN / 16)), dim3(512), 0, stream>>>(
            X, Wih0, bih0, bhh0, XG);
        lstm2_fused<float><<<dim3(BATCH), dim3(512), 0, stream>>>(
            XG, Whh0, Wih1, Whh1, bih1, bhh1, Out);
    } else if (ws_size >= NG * sizeof(_Float16)) {
        _Float16* XG = (_Float16*)d_ws;
        xg_precompute<_Float16><<<dim3(BATCH * (TLEN / 16)), dim3(512), 0, stream>>>(
            X, Wih0, bih0, bhh0, XG);
        lstm2_fused<_Float16><<<dim3(BATCH), dim3(512), 0, stream>>>(
            XG, Whh0, Wih1, Whh1, bih1, bhh1, Out);
    } else {
        lstm2_persist<<<dim3(BATCH), dim3(512), 0, stream>>>(
            X, Wih0, Whh0, bih0, bhh0, Wih1, Whh1, bih1, bhh1, Out);
    }
}